// Round 1
// baseline (2234.006 us; speedup 1.0000x reference)
//
#include <hip/hip_runtime.h>
#include <hip/hip_bf16.h>

// Problem dims (fixed by the reference)
#define M_TOTAL 8192     // B*T = 4*2048
#define K_DIM   4096     // n (input dim, normalized over)
#define H_DIM   16384    // n_hidden

#define BM 128
#define BH 128
#define BK 64

typedef __attribute__((ext_vector_type(8))) short   short8;   // 8 bf16 = 4 VGPRs
typedef __attribute__((ext_vector_type(4))) float   f32x4;
typedef __attribute__((ext_vector_type(8))) unsigned short u16x8;

// RNE float -> bf16 (bit-exact with HW cvt for normal values; NaN path irrelevant here)
static __device__ __forceinline__ unsigned short f2bf(float f) {
    unsigned int x = __float_as_uint(f);
    x += 0x7fffu + ((x >> 16) & 1u);
    return (unsigned short)(x >> 16);
}

// ---------------------------------------------------------------------------
// Kernel 1: straight cast g (fp32, [M][K]) -> bf16
// ---------------------------------------------------------------------------
__global__ void cast_bf16_kernel(const float* __restrict__ in,
                                 unsigned short* __restrict__ out, long n) {
    long i = ((long)blockIdx.x * blockDim.x + threadIdx.x) * 8;
    if (i >= n) return;
    const float4* p = (const float4*)(in + i);
    float4 a = p[0];
    float4 b = p[1];
    u16x8 o;
    o[0] = f2bf(a.x); o[1] = f2bf(a.y); o[2] = f2bf(a.z); o[3] = f2bf(a.w);
    o[4] = f2bf(b.x); o[5] = f2bf(b.y); o[6] = f2bf(b.z); o[7] = f2bf(b.w);
    *(u16x8*)(out + i) = o;
}

// ---------------------------------------------------------------------------
// Kernel 2: W [K][H] fp32 -> Wt [H][K] bf16  (LDS 64x64 tile transpose)
//           + fused column sum-of-squares into norm2[H]
// ---------------------------------------------------------------------------
__global__ void transpose_norm_kernel(const float* __restrict__ W,
                                      unsigned short* __restrict__ Wt,
                                      float* __restrict__ norm2) {
    __shared__ float tile[64][65];   // +1 pad: conflict-free transposed reads
    __shared__ float np[64];
    const int h0 = blockIdx.x * 64;
    const int n0 = blockIdx.y * 64;
    const int t  = threadIdx.x;
    const int c  = t & 63;           // fast dim (coalesced)
    const int r4 = t >> 6;           // 0..3

    if (t < 64) np[t] = 0.f;
    __syncthreads();

    float sq = 0.f;
#pragma unroll
    for (int it = 0; it < 16; ++it) {
        int r = it * 4 + r4;
        float v = W[(size_t)(n0 + r) * H_DIM + h0 + c];
        tile[r][c] = v;
        sq += v * v;
    }
    atomicAdd(&np[c], sq);           // LDS atomic, 4-way per h-column
    __syncthreads();

#pragma unroll
    for (int it = 0; it < 16; ++it) {
        int r2 = it * 4 + r4;        // h-offset within tile
        Wt[(size_t)(h0 + r2) * K_DIM + n0 + c] = f2bf(tile[c][r2]);
    }
    if (t < 64) atomicAdd(&norm2[h0 + t], np[t]);
}

// ---------------------------------------------------------------------------
// Kernel 3: fused GEMM (bf16 MFMA) + epilogue exp / per-row sum / atomicAdd
//   A  = gbf [M][K]  bf16
//   Bt = Wt  [H][K]  bf16  (transposed so B-fragments are k-contiguous)
//   score[m][h] = (A·B)[m][h] * rsqrt(norm2[h]);  sums[m] += sum_h exp(score)
// ---------------------------------------------------------------------------
__global__ __launch_bounds__(256)
void gemm_lse_kernel(const unsigned short* __restrict__ A,
                     const unsigned short* __restrict__ Bt,
                     const float* __restrict__ norm2,
                     float* __restrict__ sums) {
    __shared__ unsigned short As[BM * BK];   // 16 KB, row-major pitch 64 el = 128 B
    __shared__ unsigned short Bs[BH * BK];   // 16 KB

    const int tid  = threadIdx.x;
    const int wave = tid >> 6;
    const int lane = tid & 63;
    const int m0   = blockIdx.y * BM;
    const int h0   = blockIdx.x * BH;
    const int wm   = (wave >> 1) * 64;       // wave's m-offset in tile
    const int wh   = (wave & 1) * 64;        // wave's h-offset in tile
    const int l15  = lane & 15;
    const int quad = lane >> 4;

    f32x4 acc[4][4];
#pragma unroll
    for (int i = 0; i < 4; ++i)
#pragma unroll
        for (int j = 0; j < 4; ++j)
            acc[i][j] = (f32x4){0.f, 0.f, 0.f, 0.f};

    // Staging map: per global_load_lds issue a wave writes 1 KB = 8 rows x 128 B.
    // lane l -> row (l>>3), col-bytes (l&7)*16.  LDS base is wave-uniform.
    const int srow = lane >> 3;
    const int scol = (lane & 7) * 8;   // element offset
    const unsigned short* ag = A  + (size_t)(m0 + wave * 8 + srow) * K_DIM + scol;
    const unsigned short* bg = Bt + (size_t)(h0 + wave * 8 + srow) * K_DIM + scol;

    for (int k0 = 0; k0 < K_DIM; k0 += BK) {
#pragma unroll
        for (int i = 0; i < 4; ++i) {
            __builtin_amdgcn_global_load_lds(
                (const __attribute__((address_space(1))) void*)(ag + (size_t)i * 32 * K_DIM + k0),
                (__attribute__((address_space(3))) void*)&As[(wave * 8 + i * 32) * BK],
                16, 0, 0);
            __builtin_amdgcn_global_load_lds(
                (const __attribute__((address_space(1))) void*)(bg + (size_t)i * 32 * K_DIM + k0),
                (__attribute__((address_space(3))) void*)&Bs[(wave * 8 + i * 32) * BK],
                16, 0, 0);
        }
        __syncthreads();

#pragma unroll
        for (int kt = 0; kt < 2; ++kt) {
            const int ko = kt * 32 + quad * 8;
            short8 af[4], bf[4];
#pragma unroll
            for (int i = 0; i < 4; ++i)
                af[i] = *(const short8*)&As[(wm + i * 16 + l15) * BK + ko];
#pragma unroll
            for (int j = 0; j < 4; ++j)
                bf[j] = *(const short8*)&Bs[(wh + j * 16 + l15) * BK + ko];
#pragma unroll
            for (int i = 0; i < 4; ++i)
#pragma unroll
                for (int j = 0; j < 4; ++j)
                    acc[i][j] = __builtin_amdgcn_mfma_f32_16x16x32_bf16(
                        af[i], bf[j], acc[i][j], 0, 0, 0);
        }
        __syncthreads();
    }

    // Epilogue. C/D layout: row = quad*4 + reg, col = lane&15.
    float rn[4];
#pragma unroll
    for (int j = 0; j < 4; ++j)
        rn[j] = rsqrtf(norm2[h0 + wh + j * 16 + l15]);

#pragma unroll
    for (int i = 0; i < 4; ++i) {
#pragma unroll
        for (int r = 0; r < 4; ++r) {
            float s = 0.f;
#pragma unroll
            for (int j = 0; j < 4; ++j)
                s += __expf(acc[i][j][r] * rn[j]);
            // reduce the 16 lanes of this quad (they share the same row)
            s += __shfl_xor(s, 1);
            s += __shfl_xor(s, 2);
            s += __shfl_xor(s, 4);
            s += __shfl_xor(s, 8);
            if (l15 == 0)
                atomicAdd(&sums[m0 + wm + i * 16 + quad * 4 + r], s);
        }
    }
}

// ---------------------------------------------------------------------------
// Kernel 4: out[m] = log(sums[m])   (BETA = 1)
// ---------------------------------------------------------------------------
__global__ void finalize_kernel(const float* __restrict__ sums,
                                float* __restrict__ out, int n) {
    int i = blockIdx.x * blockDim.x + threadIdx.x;
    if (i < n) out[i] = logf(sums[i]);
}

// ---------------------------------------------------------------------------
extern "C" void kernel_launch(void* const* d_in, const int* in_sizes, int n_in,
                              void* d_out, int out_size, void* d_ws, size_t ws_size,
                              hipStream_t stream) {
    const float* g = (const float*)d_in[0];   // [4,2048,4096] fp32
    const float* W = (const float*)d_in[1];   // [4096,16384] fp32
    float* out = (float*)d_out;               // [8192] fp32

    char* ws = (char*)d_ws;
    unsigned short* gbf   = (unsigned short*)ws;                              // 64 MB
    unsigned short* wt    = (unsigned short*)(ws + (size_t)67108864);         // 128 MB
    float*          norm2 = (float*)(ws + (size_t)67108864 + 134217728);      // 64 KB
    float*          sums  = (float*)(ws + (size_t)67108864 + 134217728 + 65536); // 32 KB

    // zero norm2 + sums (contiguous)
    hipMemsetAsync(norm2, 0, (H_DIM + M_TOTAL) * sizeof(float), stream);

    cast_bf16_kernel<<<(M_TOTAL * (long)K_DIM) / (256 * 8), 256, 0, stream>>>(
        g, gbf, (long)M_TOTAL * K_DIM);

    transpose_norm_kernel<<<dim3(H_DIM / 64, K_DIM / 64), 256, 0, stream>>>(
        W, wt, norm2);

    gemm_lse_kernel<<<dim3(H_DIM / BH, M_TOTAL / BM), 256, 0, stream>>>(
        gbf, wt, norm2, sums);

    finalize_kernel<<<(M_TOTAL + 255) / 256, 256, 0, stream>>>(sums, out, M_TOTAL);
}

// Round 2
// 2036.192 us; speedup vs baseline: 1.0971x; 1.0971x over previous
//
#include <hip/hip_runtime.h>
#include <hip/hip_bf16.h>

// Problem dims (fixed by the reference)
#define M_TOTAL 8192     // B*T = 4*2048
#define K_DIM   4096     // n (input dim, normalized over)
#define H_DIM   16384    // n_hidden

#define BM 128
#define BH 128
#define BK 64

typedef __attribute__((ext_vector_type(8))) short   short8;   // 8 bf16 = 4 VGPRs
typedef __attribute__((ext_vector_type(4))) float   f32x4;
typedef __attribute__((ext_vector_type(8))) unsigned short u16x8;

// RNE float -> bf16
static __device__ __forceinline__ unsigned short f2bf(float f) {
    unsigned int x = __float_as_uint(f);
    x += 0x7fffu + ((x >> 16) & 1u);
    return (unsigned short)(x >> 16);
}

// ---------------------------------------------------------------------------
// Kernel 1: straight cast g (fp32, [M][K]) -> bf16
// ---------------------------------------------------------------------------
__global__ void cast_bf16_kernel(const float* __restrict__ in,
                                 unsigned short* __restrict__ out, long n) {
    long i = ((long)blockIdx.x * blockDim.x + threadIdx.x) * 8;
    if (i >= n) return;
    const float4* p = (const float4*)(in + i);
    float4 a = p[0];
    float4 b = p[1];
    u16x8 o;
    o[0] = f2bf(a.x); o[1] = f2bf(a.y); o[2] = f2bf(a.z); o[3] = f2bf(a.w);
    o[4] = f2bf(b.x); o[5] = f2bf(b.y); o[6] = f2bf(b.z); o[7] = f2bf(b.w);
    *(u16x8*)(out + i) = o;
}

// ---------------------------------------------------------------------------
// Kernel 2: W [K][H] fp32 -> Wt [H][K] bf16  (LDS 64x64 tile transpose)
//           + fused column sum-of-squares into norm2[H]
//           write phase vectorized: ushort8 (16B) per lane
// ---------------------------------------------------------------------------
__global__ void transpose_norm_kernel(const float* __restrict__ W,
                                      unsigned short* __restrict__ Wt,
                                      float* __restrict__ norm2) {
    __shared__ float tile[64][65];   // +1 pad
    __shared__ float np[64];
    const int h0 = blockIdx.x * 64;
    const int n0 = blockIdx.y * 64;
    const int t  = threadIdx.x;
    const int c  = t & 63;           // fast dim (coalesced global read over h)
    const int r4 = t >> 6;           // 0..3

    if (t < 64) np[t] = 0.f;
    __syncthreads();

    float sq = 0.f;
#pragma unroll
    for (int it = 0; it < 16; ++it) {
        int r = it * 4 + r4;         // n-row within tile
        float v = W[(size_t)(n0 + r) * H_DIM + h0 + c];
        tile[r][c] = v;              // tile[n][h]
        sq += v * v;
    }
    atomicAdd(&np[c], sq);           // LDS atomic, per h-column
    __syncthreads();

    // Write: Wt[h][n], each lane emits 16B (8 bf16 along n)
    const int chunk = t & 7;         // n-chunk (8 elements)
    const int hr    = t >> 3;        // 0..31
#pragma unroll
    for (int it = 0; it < 2; ++it) {
        int hrow = hr + it * 32;
        u16x8 o;
#pragma unroll
        for (int j = 0; j < 8; ++j)
            o[j] = f2bf(tile[chunk * 8 + j][hrow]);
        *(u16x8*)&Wt[(size_t)(h0 + hrow) * K_DIM + n0 + chunk * 8] = o;
    }
    if (t < 64) atomicAdd(&norm2[h0 + t], np[t]);
}

// ---------------------------------------------------------------------------
// Kernel 3: fused GEMM (bf16 MFMA) + epilogue exp / per-row sum / atomicAdd
//   LDS layout uses an XOR-8 chunk swizzle: 16B chunk c of row r lives at
//   byte r*128 + (c ^ (r&7))*16.  global_load_lds lanes fetch the permuted
//   global chunk so the DMA's forced lane-contiguous LDS write lands right.
// ---------------------------------------------------------------------------
__global__ __launch_bounds__(256)
void gemm_lse_kernel(const unsigned short* __restrict__ A,
                     const unsigned short* __restrict__ Bt,
                     const float* __restrict__ norm2,
                     float* __restrict__ sums) {
    __shared__ unsigned short As[BM * BK];   // 16 KB
    __shared__ unsigned short Bs[BH * BK];   // 16 KB

    const int tid  = threadIdx.x;
    const int wave = tid >> 6;
    const int lane = tid & 63;
    const int m0   = blockIdx.y * BM;
    const int h0   = blockIdx.x * BH;
    const int wm   = (wave >> 1) * 64;
    const int wh   = (wave & 1) * 64;
    const int l15  = lane & 15;
    const int quad = lane >> 4;

    f32x4 acc[4][4];
#pragma unroll
    for (int i = 0; i < 4; ++i)
#pragma unroll
        for (int j = 0; j < 4; ++j)
            acc[i][j] = (f32x4){0.f, 0.f, 0.f, 0.f};

    // Staging: per issue a wave writes 1 KB = 8 rows x 128 B to LDS at
    // base + lane*16.  lane -> row (lane>>3); source chunk is the XOR-swizzled
    // one: c = (lane&7) ^ (lane>>3), so LDS slot (lane&7) holds chunk c.
    const int srow = lane >> 3;                      // 0..7
    const int scol = ((lane & 7) ^ srow) * 8;        // element offset in row
    const unsigned short* ag = A  + (size_t)(m0 + wave * 8 + srow) * K_DIM + scol;
    const unsigned short* bg = Bt + (size_t)(h0 + wave * 8 + srow) * K_DIM + scol;

    for (int k0 = 0; k0 < K_DIM; k0 += BK) {
#pragma unroll
        for (int i = 0; i < 4; ++i) {
            __builtin_amdgcn_global_load_lds(
                (const __attribute__((address_space(1))) void*)(ag + (size_t)i * 32 * K_DIM + k0),
                (__attribute__((address_space(3))) void*)&As[(wave * 8 + i * 32) * BK],
                16, 0, 0);
            __builtin_amdgcn_global_load_lds(
                (const __attribute__((address_space(1))) void*)(bg + (size_t)i * 32 * K_DIM + k0),
                (__attribute__((address_space(3))) void*)&Bs[(wave * 8 + i * 32) * BK],
                16, 0, 0);
        }
        __syncthreads();

#pragma unroll
        for (int kt = 0; kt < 2; ++kt) {
            short8 af[4], bf[4];
#pragma unroll
            for (int i = 0; i < 4; ++i) {
                int row = wm + i * 16 + l15;
                int cs  = ((kt * 4 + quad) ^ (l15 & 7)) * 8;   // swizzled chunk
                af[i] = *(const short8*)&As[row * BK + cs];
            }
#pragma unroll
            for (int j = 0; j < 4; ++j) {
                int row = wh + j * 16 + l15;
                int cs  = ((kt * 4 + quad) ^ (l15 & 7)) * 8;
                bf[j] = *(const short8*)&Bs[row * BK + cs];
            }
#pragma unroll
            for (int i = 0; i < 4; ++i)
#pragma unroll
                for (int j = 0; j < 4; ++j)
                    acc[i][j] = __builtin_amdgcn_mfma_f32_16x16x32_bf16(
                        af[i], bf[j], acc[i][j], 0, 0, 0);
        }
        __syncthreads();
    }

    // Epilogue. C/D layout: row = quad*4 + reg, col = lane&15.
    float rn[4];
#pragma unroll
    for (int j = 0; j < 4; ++j)
        rn[j] = rsqrtf(norm2[h0 + wh + j * 16 + l15]);

#pragma unroll
    for (int i = 0; i < 4; ++i) {
#pragma unroll
        for (int r = 0; r < 4; ++r) {
            float s = 0.f;
#pragma unroll
            for (int j = 0; j < 4; ++j)
                s += __expf(acc[i][j][r] * rn[j]);
            s += __shfl_xor(s, 1);
            s += __shfl_xor(s, 2);
            s += __shfl_xor(s, 4);
            s += __shfl_xor(s, 8);
            if (l15 == 0)
                atomicAdd(&sums[m0 + wm + i * 16 + quad * 4 + r], s);
        }
    }
}

// ---------------------------------------------------------------------------
// Kernel 4: out[m] = log(sums[m])   (BETA = 1)
// ---------------------------------------------------------------------------
__global__ void finalize_kernel(const float* __restrict__ sums,
                                float* __restrict__ out, int n) {
    int i = blockIdx.x * blockDim.x + threadIdx.x;
    if (i < n) out[i] = logf(sums[i]);
}

// ---------------------------------------------------------------------------
extern "C" void kernel_launch(void* const* d_in, const int* in_sizes, int n_in,
                              void* d_out, int out_size, void* d_ws, size_t ws_size,
                              hipStream_t stream) {
    const float* g = (const float*)d_in[0];   // [4,2048,4096] fp32
    const float* W = (const float*)d_in[1];   // [4096,16384] fp32
    float* out = (float*)d_out;               // [8192] fp32

    char* ws = (char*)d_ws;
    unsigned short* gbf   = (unsigned short*)ws;                              // 64 MB
    unsigned short* wt    = (unsigned short*)(ws + (size_t)67108864);         // 128 MB
    float*          norm2 = (float*)(ws + (size_t)67108864 + 134217728);      // 64 KB
    float*          sums  = (float*)(ws + (size_t)67108864 + 134217728 + 65536); // 32 KB

    hipMemsetAsync(norm2, 0, (H_DIM + M_TOTAL) * sizeof(float), stream);

    cast_bf16_kernel<<<(M_TOTAL * (long)K_DIM) / (256 * 8), 256, 0, stream>>>(
        g, gbf, (long)M_TOTAL * K_DIM);

    transpose_norm_kernel<<<dim3(H_DIM / 64, K_DIM / 64), 256, 0, stream>>>(
        W, wt, norm2);

    gemm_lse_kernel<<<dim3(H_DIM / BH, M_TOTAL / BM), 256, 0, stream>>>(
        gbf, wt, norm2, sums);

    finalize_kernel<<<(M_TOTAL + 255) / 256, 256, 0, stream>>>(sums, out, M_TOTAL);
}

// Round 3
// 1765.201 us; speedup vs baseline: 1.2656x; 1.1535x over previous
//
#include <hip/hip_runtime.h>
#include <hip/hip_bf16.h>

// Problem dims (fixed by the reference)
#define M_TOTAL 8192     // B*T = 4*2048
#define K_DIM   4096     // n (input dim, normalized over)
#define H_DIM   16384    // n_hidden

#define BM 128
#define BH 128
#define BK 64

typedef __attribute__((ext_vector_type(8))) short   short8;   // 8 bf16 = 4 VGPRs
typedef __attribute__((ext_vector_type(4))) float   f32x4;
typedef __attribute__((ext_vector_type(8))) unsigned short u16x8;

// RNE float -> bf16
static __device__ __forceinline__ unsigned short f2bf(float f) {
    unsigned int x = __float_as_uint(f);
    x += 0x7fffu + ((x >> 16) & 1u);
    return (unsigned short)(x >> 16);
}

// ---------------------------------------------------------------------------
// Kernel 1: straight cast g (fp32, [M][K]) -> bf16
// ---------------------------------------------------------------------------
__global__ void cast_bf16_kernel(const float* __restrict__ in,
                                 unsigned short* __restrict__ out, long n) {
    long i = ((long)blockIdx.x * blockDim.x + threadIdx.x) * 8;
    if (i >= n) return;
    const float4* p = (const float4*)(in + i);
    float4 a = p[0];
    float4 b = p[1];
    u16x8 o;
    o[0] = f2bf(a.x); o[1] = f2bf(a.y); o[2] = f2bf(a.z); o[3] = f2bf(a.w);
    o[4] = f2bf(b.x); o[5] = f2bf(b.y); o[6] = f2bf(b.z); o[7] = f2bf(b.w);
    *(u16x8*)(out + i) = o;
}

// ---------------------------------------------------------------------------
// Kernel 2: W [K][H] fp32 -> Wt [H][K] bf16  (LDS 64x64 tile transpose)
//           + fused column sum-of-squares into norm2[H]
// ---------------------------------------------------------------------------
__global__ void transpose_norm_kernel(const float* __restrict__ W,
                                      unsigned short* __restrict__ Wt,
                                      float* __restrict__ norm2) {
    __shared__ float tile[64][65];   // +1 pad
    __shared__ float np[64];
    const int h0 = blockIdx.x * 64;
    const int n0 = blockIdx.y * 64;
    const int t  = threadIdx.x;
    const int c  = t & 63;           // fast dim (coalesced global read over h)
    const int r4 = t >> 6;           // 0..3

    if (t < 64) np[t] = 0.f;
    __syncthreads();

    float sq = 0.f;
#pragma unroll
    for (int it = 0; it < 16; ++it) {
        int r = it * 4 + r4;         // n-row within tile
        float v = W[(size_t)(n0 + r) * H_DIM + h0 + c];
        tile[r][c] = v;              // tile[n][h]
        sq += v * v;
    }
    atomicAdd(&np[c], sq);           // LDS atomic, per h-column
    __syncthreads();

    // Write: Wt[h][n], each lane emits 16B (8 bf16 along n)
    const int chunk = t & 7;         // n-chunk (8 elements)
    const int hr    = t >> 3;        // 0..31
#pragma unroll
    for (int it = 0; it < 2; ++it) {
        int hrow = hr + it * 32;
        u16x8 o;
#pragma unroll
        for (int j = 0; j < 8; ++j)
            o[j] = f2bf(tile[chunk * 8 + j][hrow]);
        *(u16x8*)&Wt[(size_t)(h0 + hrow) * K_DIM + n0 + chunk * 8] = o;
    }
    if (t < 64) atomicAdd(&norm2[h0 + t], np[t]);
}

// ---------------------------------------------------------------------------
// Kernel 3: fused GEMM (bf16 MFMA) + epilogue exp / per-row sum / atomicAdd
//   - XOR-8 chunk swizzle in LDS (conflict-free, DMA-compatible)
//   - XCD-banded group swizzle of the block->tile map for L2/LLC locality:
//     xcd = bid&7 owns a 16-h-block band; within, 8x8 (m,h) groups of 64
//     consecutive blocks share 8 A-strips + 8 B-strips (hot k-slice fits L2).
// ---------------------------------------------------------------------------
__global__ __launch_bounds__(256)
void gemm_lse_kernel(const unsigned short* __restrict__ A,
                     const unsigned short* __restrict__ Bt,
                     const float* __restrict__ norm2,
                     float* __restrict__ sums) {
    __shared__ unsigned short As[BM * BK];   // 16 KB
    __shared__ unsigned short Bs[BH * BK];   // 16 KB

    const int tid  = threadIdx.x;
    const int wave = tid >> 6;
    const int lane = tid & 63;

    // ---- block -> (m0, h0) swizzle ----
    // grid = 8192 blocks. 128 h-blocks x 64 m-blocks.
    const int bid = blockIdx.x;
    const int xcd = bid & 7;         // dispatch round-robins XCDs (heuristic)
    const int r   = bid >> 3;        // 0..1023, consecutive within an XCD
    const int grp = r >> 6;          // 16 groups of 64 blocks
    const int w   = r & 63;
    const int gh  = grp & 1;         // 2 h-groups per band
    const int gm  = grp >> 1;        // 8 m-groups
    const int hb  = xcd * 16 + gh * 8 + (w & 7);   // 0..127
    const int mb  = gm * 8 + (w >> 3);             // 0..63
    const int m0  = mb * BM;
    const int h0  = hb * BH;

    const int wm   = (wave >> 1) * 64;
    const int wh   = (wave & 1) * 64;
    const int l15  = lane & 15;
    const int quad = lane >> 4;

    f32x4 acc[4][4];
#pragma unroll
    for (int i = 0; i < 4; ++i)
#pragma unroll
        for (int j = 0; j < 4; ++j)
            acc[i][j] = (f32x4){0.f, 0.f, 0.f, 0.f};

    // Staging: per issue a wave writes 1 KB = 8 rows x 128 B to LDS at
    // base + lane*16.  lane -> row (lane>>3); source chunk is the XOR-swizzled
    // one: c = (lane&7) ^ (lane>>3), so LDS slot (lane&7) holds chunk c.
    const int srow = lane >> 3;                      // 0..7
    const int scol = ((lane & 7) ^ srow) * 8;        // element offset in row
    const unsigned short* ag = A  + (size_t)(m0 + wave * 8 + srow) * K_DIM + scol;
    const unsigned short* bg = Bt + (size_t)(h0 + wave * 8 + srow) * K_DIM + scol;

    for (int k0 = 0; k0 < K_DIM; k0 += BK) {
#pragma unroll
        for (int i = 0; i < 4; ++i) {
            __builtin_amdgcn_global_load_lds(
                (const __attribute__((address_space(1))) void*)(ag + (size_t)i * 32 * K_DIM + k0),
                (__attribute__((address_space(3))) void*)&As[(wave * 8 + i * 32) * BK],
                16, 0, 0);
            __builtin_amdgcn_global_load_lds(
                (const __attribute__((address_space(1))) void*)(bg + (size_t)i * 32 * K_DIM + k0),
                (__attribute__((address_space(3))) void*)&Bs[(wave * 8 + i * 32) * BK],
                16, 0, 0);
        }
        __syncthreads();

#pragma unroll
        for (int kt = 0; kt < 2; ++kt) {
            short8 af[4], bf[4];
#pragma unroll
            for (int i = 0; i < 4; ++i) {
                int row = wm + i * 16 + l15;
                int cs  = ((kt * 4 + quad) ^ (l15 & 7)) * 8;   // swizzled chunk
                af[i] = *(const short8*)&As[row * BK + cs];
            }
#pragma unroll
            for (int j = 0; j < 4; ++j) {
                int row = wh + j * 16 + l15;
                int cs  = ((kt * 4 + quad) ^ (l15 & 7)) * 8;
                bf[j] = *(const short8*)&Bs[row * BK + cs];
            }
#pragma unroll
            for (int i = 0; i < 4; ++i)
#pragma unroll
                for (int j = 0; j < 4; ++j)
                    acc[i][j] = __builtin_amdgcn_mfma_f32_16x16x32_bf16(
                        af[i], bf[j], acc[i][j], 0, 0, 0);
        }
        __syncthreads();
    }

    // Epilogue. C/D layout: row = quad*4 + reg, col = lane&15.
    float rn[4];
#pragma unroll
    for (int j = 0; j < 4; ++j)
        rn[j] = rsqrtf(norm2[h0 + wh + j * 16 + l15]);

#pragma unroll
    for (int i = 0; i < 4; ++i) {
#pragma unroll
        for (int r2 = 0; r2 < 4; ++r2) {
            float s = 0.f;
#pragma unroll
            for (int j = 0; j < 4; ++j)
                s += __expf(acc[i][j][r2] * rn[j]);
            s += __shfl_xor(s, 1);
            s += __shfl_xor(s, 2);
            s += __shfl_xor(s, 4);
            s += __shfl_xor(s, 8);
            if (l15 == 0)
                atomicAdd(&sums[m0 + wm + i * 16 + quad * 4 + r2], s);
        }
    }
}

// ---------------------------------------------------------------------------
// Kernel 4: out[m] = log(sums[m])   (BETA = 1)
// ---------------------------------------------------------------------------
__global__ void finalize_kernel(const float* __restrict__ sums,
                                float* __restrict__ out, int n) {
    int i = blockIdx.x * blockDim.x + threadIdx.x;
    if (i < n) out[i] = logf(sums[i]);
}

// ---------------------------------------------------------------------------
extern "C" void kernel_launch(void* const* d_in, const int* in_sizes, int n_in,
                              void* d_out, int out_size, void* d_ws, size_t ws_size,
                              hipStream_t stream) {
    const float* g = (const float*)d_in[0];   // [4,2048,4096] fp32
    const float* W = (const float*)d_in[1];   // [4096,16384] fp32
    float* out = (float*)d_out;               // [8192] fp32

    char* ws = (char*)d_ws;
    unsigned short* gbf   = (unsigned short*)ws;                              // 64 MB
    unsigned short* wt    = (unsigned short*)(ws + (size_t)67108864);         // 128 MB
    float*          norm2 = (float*)(ws + (size_t)67108864 + 134217728);      // 64 KB
    float*          sums  = (float*)(ws + (size_t)67108864 + 134217728 + 65536); // 32 KB

    hipMemsetAsync(norm2, 0, (H_DIM + M_TOTAL) * sizeof(float), stream);

    cast_bf16_kernel<<<(M_TOTAL * (long)K_DIM) / (256 * 8), 256, 0, stream>>>(
        g, gbf, (long)M_TOTAL * K_DIM);

    transpose_norm_kernel<<<dim3(H_DIM / 64, K_DIM / 64), 256, 0, stream>>>(
        W, wt, norm2);

    gemm_lse_kernel<<<(H_DIM / BH) * (M_TOTAL / BM), 256, 0, stream>>>(
        gbf, wt, norm2, sums);

    finalize_kernel<<<(M_TOTAL + 255) / 256, 256, 0, stream>>>(sums, out, M_TOTAL);
}